// Round 1
// 1604.159 us; speedup vs baseline: 1.0904x; 1.0904x over previous
//
#include <hip/hip_runtime.h>

#define N_NODES 100000
#define N_EDGES 1600000
#define HID 64
#define EDIM 32
#define BN_EPS 1e-5f

#define SCAN_CHUNK 1024
#define NB_SCAN ((N_NODES + SCAN_CHUNK - 1) / SCAN_CHUNK)   // 98

#define G_NODES 16                       // dst nodes per block (gather)
#define CAP 160                          // edges staged in LDS per chunk
#define S_ATTR_F4 (CAP * 8 + 64)         // +64 float4 pad for DMA tail overrun
#define S_SRC_I   (CAP + 64)             // +64 int pad for DMA tail overrun
#define N_EPS ((CAP * 8 + 255) / 256)    // staging iterations per thread (5)

// ---------------------------------------------------------------------------
// Counting sort of edges by dst.  Built once per call, reused by all 3 layers.
// ---------------------------------------------------------------------------
__global__ __launch_bounds__(256) void hist_kernel(
    const int* __restrict__ dst, int* __restrict__ cnt)
{
    int i = (int)(blockIdx.x * blockDim.x + threadIdx.x);
    const int stride = (int)(gridDim.x * blockDim.x);
    for (; i < N_EDGES; i += stride) atomicAdd(&cnt[dst[i]], 1);
}

__global__ __launch_bounds__(256) void scan1_kernel(
    const int* __restrict__ cnt, int* __restrict__ bsum)
{
    __shared__ int s[256];
    const int b = (int)blockIdx.x, t = (int)threadIdx.x;
    const int base = b * SCAN_CHUNK + t * 4;
    int sum = 0;
#pragma unroll
    for (int k = 0; k < 4; ++k) {
        int idx = base + k;
        if (idx < N_NODES) sum += cnt[idx];
    }
    s[t] = sum;
    __syncthreads();
    for (int off = 128; off > 0; off >>= 1) {
        if (t < off) s[t] += s[t + off];
        __syncthreads();
    }
    if (t == 0) bsum[b] = s[0];
}

__global__ __launch_bounds__(128) void scan2_kernel(
    const int* __restrict__ bsum, int* __restrict__ bofs, int* __restrict__ row_ptr)
{
    __shared__ int s[128];
    const int t = (int)threadIdx.x;
    const int v = (t < NB_SCAN) ? bsum[t] : 0;
    s[t] = v;
    __syncthreads();
    for (int off = 1; off < 128; off <<= 1) {
        int add = (t >= off) ? s[t - off] : 0;
        __syncthreads();
        s[t] += add;
        __syncthreads();
    }
    if (t < NB_SCAN) bofs[t] = s[t] - v;
    if (t == NB_SCAN - 1) row_ptr[N_NODES] = s[t];
}

__global__ __launch_bounds__(256) void scan3_kernel(
    const int* __restrict__ cnt, const int* __restrict__ bofs,
    int* __restrict__ row_ptr, int* __restrict__ pos)
{
    __shared__ int s[256];
    const int b = (int)blockIdx.x, t = (int)threadIdx.x;
    const int base = b * SCAN_CHUNK + t * 4;
    int v[4];
    int sum = 0;
#pragma unroll
    for (int k = 0; k < 4; ++k) {
        int idx = base + k;
        v[k] = (idx < N_NODES) ? cnt[idx] : 0;
        sum += v[k];
    }
    s[t] = sum;
    __syncthreads();
    for (int off = 1; off < 256; off <<= 1) {
        int add = (t >= off) ? s[t - off] : 0;
        __syncthreads();
        s[t] += add;
        __syncthreads();
    }
    int run = s[t] - sum + bofs[b];
#pragma unroll
    for (int k = 0; k < 4; ++k) {
        int idx = base + k;
        if (idx < N_NODES) {
            row_ptr[idx] = run;
            pos[idx] = run;
            run += v[k];
        }
    }
}

__global__ __launch_bounds__(256) void scatter_kernel(
    const int* __restrict__ src, const int* __restrict__ dst,
    int* __restrict__ pos, int* __restrict__ perm_e, int* __restrict__ perm_src)
{
    int i = (int)(blockIdx.x * blockDim.x + threadIdx.x);
    const int stride = (int)(gridDim.x * blockDim.x);
    for (; i < N_EDGES; i += stride) {
        const int d = dst[i];
        const int p = atomicAdd(&pos[d], 1);
        perm_e[p] = i;
        perm_src[p] = src[i];
    }
}

// ---------------------------------------------------------------------------
// Async global->LDS helpers (wave-uniform LDS base + lane*size dest;
// per-lane global source).  Size must be a literal.
// ---------------------------------------------------------------------------
__device__ __forceinline__ void gl_lds16(const float4* g, float4* l)
{
    __builtin_amdgcn_global_load_lds(
        (const __attribute__((address_space(1))) void*)g,
        (__attribute__((address_space(3))) void*)l, 16, 0, 0);
}
__device__ __forceinline__ void gl_lds4(const int* g, int* l)
{
    __builtin_amdgcn_global_load_lds(
        (const __attribute__((address_space(1))) void*)g,
        (__attribute__((address_space(3))) void*)l, 4, 0, 0);
}

// ---------------------------------------------------------------------------
// Gather, LDS-staged: block = 4 waves = 16 dst nodes = one contiguous sorted
// edge range.  Chunked: DMA-stage <=CAP edges' attr (global_load_lds, next
// chunk's perm_e preloaded into regs) + src into LDS; each wave accumulates
// its 4 nodes with broadcast ds_read_b128 attr + 4-chain FMA + flat depth-2
// x-gather pipeline.  No atomics.  CAP=160 -> ~22.4 KB LDS -> 6-7 blocks/CU.
// ---------------------------------------------------------------------------
__global__ __launch_bounds__(256, 5) void gather_staged_kernel(
    const float* __restrict__ x, const float* __restrict__ eattr,
    const int* __restrict__ row_ptr, const int* __restrict__ perm_e,
    const int* __restrict__ perm_src,
    const float* __restrict__ We, const float* __restrict__ be,
    float* __restrict__ agg)
{
    __shared__ float4 s_attr[S_ATTR_F4];   // 21504 B
    __shared__ int    s_src[S_SRC_I];      // 896 B

    const int tid  = (int)threadIdx.x;
    const int lane = tid & 63;
    const int w    = tid >> 6;                    // wave 0..3
    const int node_lo = (int)blockIdx.x * G_NODES;

    // this lane's weight column (reused for all edges of the block)
    float wv[EDIM];
#pragma unroll
    for (int k = 0; k < EDIM; ++k) wv[k] = We[k * HID + lane];
    const float bias = be[lane];

    // this wave's 4 node ranges
    int rp[5];
#pragma unroll
    for (int i = 0; i < 5; ++i) {
        int n = node_lo + 4 * w + i;
        rp[i] = row_ptr[n < N_NODES ? n : N_NODES];
    }
    float acc[4] = {0.0f, 0.0f, 0.0f, 0.0f};

    const int e0 = row_ptr[node_lo];
    const int hi = node_lo + G_NODES;
    const int e1 = row_ptr[hi < N_NODES ? hi : N_NODES];

    const float4* eattr4 = (const float4*)eattr;

    // perm_e values for the chunk being staged (preloaded one chunk ahead so
    // the dependent perm_e -> eattr chain is off the staging critical path)
    int eps[N_EPS];
    auto load_eps = [&](int cbase) {
        const int cc  = (e1 - cbase < CAP) ? (e1 - cbase) : CAP;
        const int nqq = cc * 8;
#pragma unroll
        for (int k = 0; k < N_EPS; ++k) {
            int i = w * 64 + k * 256 + lane;
            if (i >= nqq) i = nqq - 1;          // tail clamp (dup, harmless)
            eps[k] = perm_e[cbase + (i >> 3)];
        }
    };

    if (e0 < e1) load_eps(e0);

    for (int c0 = e0; c0 < e1; c0 += CAP) {
        const int cnt = (e1 - c0 < CAP) ? (e1 - c0) : CAP;
        const int nq  = cnt * 8;                // float4 count to stage
        const int c1  = c0 + cnt;

        __syncthreads();                        // LDS safe to overwrite

        // ---- stage attr rows: async DMA, 64 float4 (= 8 edge rows) / instr
#pragma unroll
        for (int k = 0; k < N_EPS; ++k) {
            const int b = w * 64 + k * 256;     // wave-uniform LDS base
            if (b < nq) {
                int i = b + lane;
                if (i >= nq) i = nq - 1;        // tail lanes fetch dup into pad
                gl_lds16(eattr4 + (size_t)eps[k] * 8 + (i & 7), s_attr + b);
            }
        }
        // ---- stage src indices (already permuted -> linear addresses)
        {
            const int b = w * 64;
            if (b < cnt) {
                int i = b + lane;
                if (i >= cnt) i = cnt - 1;
                gl_lds4(perm_src + c0 + i, s_src + b);
            }
        }
        // ---- preload next chunk's perm_e (flies under the DMA + barrier)
        if (c0 + CAP < e1) load_eps(c0 + CAP);

        __syncthreads();                        // drains vmcnt -> LDS ready

        // ---- compute: flat pipeline across this wave's range in the chunk
        int f0 = rp[0] > c0 ? rp[0] : c0;
        const int F1 = rp[4] < c1 ? rp[4] : c1;
        if (f0 < F1) {
            const int FL = F1 - 1;
            int j1 = (f0 + 1 > FL) ? FL : f0 + 1;
            int j2 = (f0 + 2 > FL) ? FL : f0 + 2;
            const int sA = s_src[f0 - c0];
            const int sB = s_src[j1 - c0];
            int si = s_src[j2 - c0];            // src idx for flat pos +2
            float xq0 = x[(size_t)sA * HID + lane];   // x row for flat pos
            float xq1 = x[(size_t)sB * HID + lane];   // x row for flat pos +1

#pragma unroll
            for (int q = 0; q < 4; ++q) {
                const int jb = (rp[q]     > c0) ? rp[q]     : c0;
                const int je = (rp[q + 1] < c1) ? rp[q + 1] : c1;
                float a = acc[q];
                for (int j = jb; j < je; ++j) {
                    // issue x prefetch for j+2 (si pre-read last iteration)
                    const float xl = x[(size_t)si * HID + lane];
                    int j3 = j + 3; if (j3 > FL) j3 = FL;
                    si = s_src[j3 - c0];

                    const float4* p = s_attr + (size_t)(j - c0) * 8;
                    // 4 independent FMA chains (8 deep each) kill the
                    // 32-deep dependent chain
                    float ee[4] = {bias, 0.0f, 0.0f, 0.0f};
#pragma unroll
                    for (int jj = 0; jj < 8; ++jj) {
                        const float4 qv = p[jj];
                        float t = ee[jj & 3];
                        t = fmaf(qv.x, wv[4 * jj + 0], t);
                        t = fmaf(qv.y, wv[4 * jj + 1], t);
                        t = fmaf(qv.z, wv[4 * jj + 2], t);
                        t = fmaf(qv.w, wv[4 * jj + 3], t);
                        ee[jj & 3] = t;
                    }
                    a += fmaxf(xq0 + ((ee[0] + ee[1]) + (ee[2] + ee[3])), 0.0f);
                    xq0 = xq1; xq1 = xl;
                }
                acc[q] = a;
            }
        }
    }

#pragma unroll
    for (int q = 0; q < 4; ++q) {
        const int n = node_lo + 4 * w + q;
        if (n < N_NODES) agg[(size_t)n * HID + lane] = acc[q];
    }
}

// ---------------------------------------------------------------------------
// MLP kernel: lane = node.  u = relu((x+agg)@W1+b1)@W2+b2
// ---------------------------------------------------------------------------
__global__ __launch_bounds__(256) void mlp_kernel(
    const float* __restrict__ xin, const float* __restrict__ agg,
    const float* __restrict__ W1, const float* __restrict__ b1,
    const float* __restrict__ W2, const float* __restrict__ b2,
    float* __restrict__ uout)
{
    const int lane = threadIdx.x & 63;
    const int wid  = (int)((blockIdx.x * blockDim.x + threadIdx.x) >> 6);
    const int n    = wid * 64 + lane;
    const bool ok  = (n < N_NODES);
    const size_t base = (size_t)n * HID;

    float h[HID];
    if (ok) {
        const float4* px = (const float4*)(xin + base);
        const float4* pa = (const float4*)(agg + base);
#pragma unroll
        for (int j = 0; j < HID / 4; ++j) {
            float4 xv = px[j];
            float4 av = pa[j];
            h[4 * j + 0] = xv.x + av.x;
            h[4 * j + 1] = xv.y + av.y;
            h[4 * j + 2] = xv.z + av.z;
            h[4 * j + 3] = xv.w + av.w;
        }
    } else {
#pragma unroll
        for (int k = 0; k < HID; ++k) h[k] = 0.0f;
    }

    float u[HID];
#pragma unroll
    for (int f = 0; f < HID; ++f) u[f] = b2[f];

    for (int c = 0; c < 4; ++c) {
        float t[16];
#pragma unroll
        for (int j = 0; j < 16; ++j) t[j] = b1[c * 16 + j];
#pragma unroll
        for (int k = 0; k < HID; ++k) {
            const float hk = h[k];
#pragma unroll
            for (int j = 0; j < 16; ++j)
                t[j] = fmaf(hk, W1[k * HID + c * 16 + j], t[j]);
        }
#pragma unroll
        for (int j = 0; j < 16; ++j) t[j] = fmaxf(t[j], 0.0f);
#pragma unroll
        for (int j = 0; j < 16; ++j) {
            const float tj = t[j];
#pragma unroll
            for (int f = 0; f < HID; ++f)
                u[f] = fmaf(tj, W2[(c * 16 + j) * HID + f], u[f]);
        }
    }

    if (ok) {
        float4* po = (float4*)(uout + base);
#pragma unroll
        for (int j = 0; j < HID / 4; ++j)
            po[j] = make_float4(u[4 * j], u[4 * j + 1], u[4 * j + 2], u[4 * j + 3]);
    }
}

// ---------------------------------------------------------------------------
// Final projection: out = x @ Wout + bout
// ---------------------------------------------------------------------------
__global__ __launch_bounds__(256) void out_kernel(
    const float* __restrict__ xin, const float* __restrict__ Wo,
    const float* __restrict__ bo, float* __restrict__ out)
{
    const int lane = threadIdx.x & 63;
    const int wid  = (int)((blockIdx.x * blockDim.x + threadIdx.x) >> 6);
    const int n    = wid * 64 + lane;
    const bool ok  = (n < N_NODES);
    const size_t base = (size_t)n * HID;

    float h[HID];
    if (ok) {
        const float4* px = (const float4*)(xin + base);
#pragma unroll
        for (int j = 0; j < HID / 4; ++j) {
            float4 xv = px[j];
            h[4 * j + 0] = xv.x; h[4 * j + 1] = xv.y;
            h[4 * j + 2] = xv.z; h[4 * j + 3] = xv.w;
        }
    } else {
#pragma unroll
        for (int k = 0; k < HID; ++k) h[k] = 0.0f;
    }

    for (int c = 0; c < 4; ++c) {
        float t[16];
#pragma unroll
        for (int j = 0; j < 16; ++j) t[j] = bo[c * 16 + j];
#pragma unroll
        for (int k = 0; k < HID; ++k) {
            const float hk = h[k];
#pragma unroll
            for (int j = 0; j < 16; ++j)
                t[j] = fmaf(hk, Wo[k * HID + c * 16 + j], t[j]);
        }
        if (ok) {
            float4* po = (float4*)(out + base + c * 16);
#pragma unroll
            for (int j = 0; j < 4; ++j)
                po[j] = make_float4(t[4 * j], t[4 * j + 1], t[4 * j + 2], t[4 * j + 3]);
        }
    }
}

// ---------------------------------------------------------------------------
// BN statistics (sum / sumsq per feature)
// ---------------------------------------------------------------------------
__global__ __launch_bounds__(256) void stats_kernel(
    const float* __restrict__ u, float* __restrict__ stats)
{
    __shared__ float ls[256];
    __shared__ float ls2[256];
    const int tid = (int)threadIdx.x;
    const int g   = (int)(blockIdx.x * 256 + tid);
    const int f   = g & 63;
    const int row = g >> 6;
    const int rstride = (int)((gridDim.x * 256) >> 6);

    float s = 0.0f, s2 = 0.0f;
    for (int n = row; n < N_NODES; n += rstride) {
        float v = u[(size_t)n * HID + f];
        s += v;
        s2 = fmaf(v, v, s2);
    }
    ls[tid] = s;
    ls2[tid] = s2;
    __syncthreads();
    if (tid < 64) {
        float a = ls[tid] + ls[tid + 64] + ls[tid + 128] + ls[tid + 192];
        float b = ls2[tid] + ls2[tid + 64] + ls2[tid + 128] + ls2[tid + 192];
        atomicAdd(&stats[tid], a);
        atomicAdd(&stats[64 + tid], b);
    }
}

// ---------------------------------------------------------------------------
// BN apply + relu
// ---------------------------------------------------------------------------
__global__ __launch_bounds__(256) void bn_relu_kernel(
    const float* __restrict__ u, const float* __restrict__ stats,
    const float* __restrict__ gamma, const float* __restrict__ beta,
    float* __restrict__ xout)
{
    const int total4 = N_NODES * HID / 4;
    int i = (int)(blockIdx.x * blockDim.x + threadIdx.x);
    const int stride = (int)(gridDim.x * blockDim.x);
    const int fb = (i * 4) & 63;

    const float invN = 1.0f / (float)N_NODES;
    float sc[4], sh[4];
#pragma unroll
    for (int j = 0; j < 4; ++j) {
        float mean = stats[fb + j] * invN;
        float var  = stats[64 + fb + j] * invN - mean * mean;
        float s    = gamma[fb + j] * rsqrtf(var + BN_EPS);
        sc[j] = s;
        sh[j] = beta[fb + j] - mean * s;
    }
    for (; i < total4; i += stride) {
        float4 v = ((const float4*)u)[i];
        v.x = fmaxf(fmaf(v.x, sc[0], sh[0]), 0.0f);
        v.y = fmaxf(fmaf(v.y, sc[1], sh[1]), 0.0f);
        v.z = fmaxf(fmaf(v.z, sc[2], sh[2]), 0.0f);
        v.w = fmaxf(fmaf(v.w, sc[3], sh[3]), 0.0f);
        ((float4*)xout)[i] = v;
    }
}

// ---------------------------------------------------------------------------
extern "C" void kernel_launch(void* const* d_in, const int* in_sizes, int n_in,
                              void* d_out, int out_size, void* d_ws, size_t ws_size,
                              hipStream_t stream)
{
    const float* x0    = (const float*)d_in[0];
    const int*   eidx  = (const int*)d_in[1];
    const float* eattr = (const float*)d_in[2];
    const float* We    = (const float*)d_in[3];
    const float* be    = (const float*)d_in[4];
    const float* W1    = (const float*)d_in[5];
    const float* b1    = (const float*)d_in[6];
    const float* W2    = (const float*)d_in[7];
    const float* b2    = (const float*)d_in[8];
    const float* gamma = (const float*)d_in[9];
    const float* beta  = (const float*)d_in[10];
    const float* Wout  = (const float*)d_in[11];
    const float* bout  = (const float*)d_in[12];
    float* out = (float*)d_out;

    const int* src = eidx;
    const int* dst = eidx + N_EDGES;

    const size_t NH = (size_t)N_NODES * HID;

    // workspace layout (fp32/int32 elements)
    float* A     = (float*)d_ws;                 // post-layer x        (NH)
    float* AGG   = A + NH;                       // segmented sums      (NH)
    float* stats = AGG + NH;                     // 128 floats
    int* cnt      = (int*)(stats + 128);         // N_NODES
    int* bsum     = cnt + N_NODES;               // NB_SCAN (pad 128)
    int* bofs     = bsum + 128;                  // NB_SCAN (pad 128)
    int* row_ptr  = bofs + 128;                  // N_NODES + 1
    int* pos      = row_ptr + N_NODES + 1;       // N_NODES
    int* perm_e   = pos + N_NODES;               // N_EDGES
    int* perm_src = perm_e + N_EDGES;            // N_EDGES
    float* B = out;                              // pre-BN MLP output (reuse d_out)

    // ---- build CSR-by-dst (once; shared by all 3 layers) ----
    hipMemsetAsync(cnt, 0, N_NODES * sizeof(int), stream);
    hist_kernel<<<1024, 256, 0, stream>>>(dst, cnt);
    scan1_kernel<<<NB_SCAN, 256, 0, stream>>>(cnt, bsum);
    scan2_kernel<<<1, 128, 0, stream>>>(bsum, bofs, row_ptr);
    scan3_kernel<<<NB_SCAN, 256, 0, stream>>>(cnt, bofs, row_ptr, pos);
    scatter_kernel<<<1024, 256, 0, stream>>>(src, dst, pos, perm_e, perm_src);

    const int mlp_blocks    = ((N_NODES + 63) / 64 + 3) / 4;           // 391
    const int gather_blocks = (N_NODES + G_NODES - 1) / G_NODES;       // 6250

    const float* xin = x0;
    for (int i = 0; i < 3; ++i) {
        hipMemsetAsync(stats, 0, 128 * sizeof(float), stream);

        gather_staged_kernel<<<gather_blocks, 256, 0, stream>>>(
            xin, eattr, row_ptr, perm_e, perm_src,
            We + (size_t)i * EDIM * HID, be + (size_t)i * HID, AGG);

        mlp_kernel<<<mlp_blocks, 256, 0, stream>>>(
            xin, AGG,
            W1 + (size_t)i * HID * HID, b1 + (size_t)i * HID,
            W2 + (size_t)i * HID * HID, b2 + (size_t)i * HID, B);

        stats_kernel<<<256, 256, 0, stream>>>(B, stats);

        bn_relu_kernel<<<1024, 256, 0, stream>>>(
            B, stats, gamma + (size_t)i * HID, beta + (size_t)i * HID, A);

        xin = A;
    }

    out_kernel<<<mlp_blocks, 256, 0, stream>>>(A, Wout, bout, out);
}